// Round 1
// baseline (401.939 us; speedup 1.0000x reference)
//
#include <hip/hip_runtime.h>

typedef __attribute__((ext_vector_type(8))) __bf16 bf16x8;
typedef __attribute__((ext_vector_type(8))) unsigned short u16x8;
typedef __attribute__((ext_vector_type(4))) float f32x4;
typedef unsigned short u16;
typedef unsigned int u32;

constexpr int Bb = 4, Ss = 2048, Ee = 1024, Hh = 16, HDd = 64;
constexpr int Mm = Bb * Ss;   // 8192
constexpr int N3 = 3 * Ee;    // 3072

__device__ __forceinline__ u16 f2bf(float f) {
  u32 u = __builtin_bit_cast(u32, f);
  u = (u + 0x7FFFu + ((u >> 16) & 1u)) >> 16;
  return (u16)u;
}

__device__ __forceinline__ void gload_lds16(const void* g, void* l) {
  __builtin_amdgcn_global_load_lds(
      (__attribute__((address_space(1))) void*)g,
      (__attribute__((address_space(3))) void*)l, 16, 0, 0);
}

__device__ __forceinline__ f32x4 mfma16(bf16x8 a, bf16x8 b, f32x4 c) {
  return __builtin_amdgcn_mfma_f32_16x16x32_bf16(a, b, c, 0, 0, 0);
}

// ---------------- cast fp32 -> bf16, flat, vectorized ----------------
__global__ void cast_x_kernel(const float* __restrict__ x, u16* __restrict__ xb, int n4) {
  int i = blockIdx.x * blockDim.x + threadIdx.x;
  int stride = gridDim.x * blockDim.x;
  for (; i < n4; i += stride) {
    float4 v = reinterpret_cast<const float4*>(x)[i];
    ushort4 o;
    o.x = f2bf(v.x); o.y = f2bf(v.y); o.z = f2bf(v.z); o.w = f2bf(v.w);
    reinterpret_cast<ushort4*>(xb)[i] = o;
  }
}

// ---------------- transpose-cast weight [K][N] fp32 -> [N][K] bf16 ----------------
__global__ void transpose_cast_kernel(const float* __restrict__ W, u16* __restrict__ Wt,
                                      int K, int N) {
  __shared__ float tile[32][33];
  int n0 = blockIdx.x * 32, k0 = blockIdx.y * 32;
  int tx = threadIdx.x & 31, ty = threadIdx.x >> 5;
#pragma unroll
  for (int i = 0; i < 4; ++i)
    tile[ty + i * 8][tx] = W[(size_t)(k0 + ty + i * 8) * N + n0 + tx];
  __syncthreads();
#pragma unroll
  for (int i = 0; i < 4; ++i)
    Wt[(size_t)(n0 + ty + i * 8) * K + k0 + tx] = f2bf(tile[tx][ty + i * 8]);
}

// ---------------- bf16 GEMM: C = A[M][K] * Bt[N][K]^T + bias ----------------
// 128x128 tile, BK=32, 256 threads = 4 waves (2x2), each wave 64x64 (4x4 frags)
template <bool OUT_BF16>
__global__ __launch_bounds__(256) void gemm_kernel(
    const u16* __restrict__ A, const u16* __restrict__ Bt,
    const float* __restrict__ bias, void* __restrict__ Cout,
    int M, int N, int K) {
  __shared__ __attribute__((aligned(16))) u16 ldsA[128 * 32];
  __shared__ __attribute__((aligned(16))) u16 ldsB[128 * 32];
  int tid = threadIdx.x;
  int lane = tid & 63, w = tid >> 6;
  int wr = w >> 1, wc = w & 1;
  int m0 = blockIdx.y * 128, n0 = blockIdx.x * 128;
  const f32x4 fz = {0.f, 0.f, 0.f, 0.f};
  f32x4 acc[4][4];
#pragma unroll
  for (int mi = 0; mi < 4; ++mi)
#pragma unroll
    for (int nj = 0; nj < 4; ++nj) acc[mi][nj] = fz;

  int srow = tid >> 2;          // 0..63
  int scol = (tid & 3) * 8;     // element offset in k-dir
  const u16* aptr = A + (size_t)(m0 + srow) * K + scol;
  const u16* bptr = Bt + (size_t)(n0 + srow) * K + scol;
  u16* la = &ldsA[srow * 32 + scol];
  u16* lb = &ldsB[srow * 32 + scol];

  for (int k0 = 0; k0 < K; k0 += 32) {
    gload_lds16(aptr + k0, la);
    gload_lds16(aptr + k0 + (size_t)64 * K, la + 64 * 32);
    gload_lds16(bptr + k0, lb);
    gload_lds16(bptr + k0 + (size_t)64 * K, lb + 64 * 32);
    __syncthreads();
    bf16x8 af[4], bfr[4];
#pragma unroll
    for (int mi = 0; mi < 4; ++mi)
      af[mi] = *(const bf16x8*)&ldsA[(wr * 64 + mi * 16 + (lane & 15)) * 32 + (lane >> 4) * 8];
#pragma unroll
    for (int nj = 0; nj < 4; ++nj)
      bfr[nj] = *(const bf16x8*)&ldsB[(wc * 64 + nj * 16 + (lane & 15)) * 32 + (lane >> 4) * 8];
#pragma unroll
    for (int mi = 0; mi < 4; ++mi)
#pragma unroll
      for (int nj = 0; nj < 4; ++nj)
        acc[mi][nj] = mfma16(af[mi], bfr[nj], acc[mi][nj]);
    __syncthreads();
  }

#pragma unroll
  for (int mi = 0; mi < 4; ++mi) {
#pragma unroll
    for (int nj = 0; nj < 4; ++nj) {
      int n = n0 + wc * 64 + nj * 16 + (lane & 15);
      float bn = bias[n];
#pragma unroll
      for (int r = 0; r < 4; ++r) {
        int m = m0 + wr * 64 + mi * 16 + (lane >> 4) * 4 + r;
        float v = acc[mi][nj][r] + bn;
        if (OUT_BF16)
          ((u16*)Cout)[(size_t)m * N + n] = f2bf(v);
        else
          ((float*)Cout)[(size_t)m * N + n] = v;
      }
    }
  }
}

// ---------------- causal flash attention ----------------
// qkv layout: [B,S,3E], head h owns cols [h*192, h*192+192) = q(64)|k(64)|v(64)
// grid: (S/64, B*H); 256 threads = 4 waves, wave w handles q rows [q0+w*16, +16)
__global__ __launch_bounds__(256) void attn_kernel(const u16* __restrict__ qkv,
                                                   u16* __restrict__ aout) {
  constexpr int LDK = 72;  // 64 + 8 pad (keeps rows 16B-aligned, spreads banks)
  __shared__ __attribute__((aligned(16))) u16 ldsK[64 * LDK];
  __shared__ __attribute__((aligned(16))) u16 ldsV[64 * LDK];  // transposed: [d][kv]
  __shared__ __attribute__((aligned(16))) u16 ldsP[4][16 * LDK];

  int qi = gridDim.x - 1 - blockIdx.x;  // big blocks first
  int bh = blockIdx.y;
  int b = bh >> 4, h = bh & 15;
  int tid = threadIdx.x, lane = tid & 63, w = tid >> 6;
  int q0 = qi * 64;
  int col16 = lane & 15;
  int myrow = (lane >> 4) * 4;

  const u16* base = qkv + (size_t)b * Ss * N3 + h * (3 * HDd);

  // Q fragments (stay in registers)
  int qrow = q0 + w * 16 + col16;
  const u16* qp = base + (size_t)qrow * N3 + (lane >> 4) * 8;
  bf16x8 qf0 = *(const bf16x8*)(qp);
  bf16x8 qf1 = *(const bf16x8*)(qp + 32);

  const f32x4 fz = {0.f, 0.f, 0.f, 0.f};
  f32x4 o0 = fz, o1 = fz, o2 = fz, o3 = fz;
  float mrun[4], lrun[4];
#pragma unroll
  for (int r = 0; r < 4; ++r) { mrun[r] = -__builtin_inff(); lrun[r] = 0.f; }

  int kvr = lane;  // staging row
  const u16* kgp = base + HDd + (size_t)kvr * N3;
  const u16* vgp = base + 2 * HDd + (size_t)kvr * N3;

  int ntiles = qi + 1;
  for (int t = 0; t < ntiles; ++t) {
    int kv0 = t * 64;
    __syncthreads();  // protect LDS from previous iteration's readers
    // ---- stage K (row-major) and V (transposed) ----
#pragma unroll
    for (int c = 0; c < 2; ++c) {
      int dc = w + c * 4;  // d-chunk 0..7
      u16x8 kk = *(const u16x8*)(kgp + (size_t)kv0 * N3 + dc * 8);
      *(u16x8*)&ldsK[kvr * LDK + dc * 8] = kk;
      u16x8 vv = *(const u16x8*)(vgp + (size_t)kv0 * N3 + dc * 8);
#pragma unroll
      for (int i = 0; i < 8; ++i)
        ldsV[(dc * 8 + i) * LDK + kvr] = vv[i];
    }
    __syncthreads();

    // ---- QK^T ----
    f32x4 sc[4];
    sc[0] = fz; sc[1] = fz; sc[2] = fz; sc[3] = fz;
#pragma unroll
    for (int kc = 0; kc < 2; ++kc) {
      bf16x8 qa = kc ? qf1 : qf0;
#pragma unroll
      for (int nj = 0; nj < 4; ++nj) {
        bf16x8 kb = *(const bf16x8*)&ldsK[(nj * 16 + col16) * LDK + kc * 32 + (lane >> 4) * 8];
        sc[nj] = mfma16(qa, kb, sc[nj]);
      }
    }

    // ---- online softmax (rows owned per-lane: (lane>>4)*4 + r) ----
    bool diag = (t == ntiles - 1);
    float p[4][4];
#pragma unroll
    for (int r = 0; r < 4; ++r) {
      int qr = q0 + w * 16 + myrow + r;
      float mx = -__builtin_inff();
#pragma unroll
      for (int nj = 0; nj < 4; ++nj) {
        float s = sc[nj][r] * 0.125f;
        if (diag && (kv0 + nj * 16 + col16) > qr) s = -__builtin_inff();
        p[nj][r] = s;
        mx = fmaxf(mx, s);
      }
      mx = fmaxf(mx, __shfl_xor(mx, 1));
      mx = fmaxf(mx, __shfl_xor(mx, 2));
      mx = fmaxf(mx, __shfl_xor(mx, 4));
      mx = fmaxf(mx, __shfl_xor(mx, 8));
      float mnew = fmaxf(mrun[r], mx);
      float corr = __expf(mrun[r] - mnew);
      mrun[r] = mnew;
      float sum = 0.f;
#pragma unroll
      for (int nj = 0; nj < 4; ++nj) {
        float e = __expf(p[nj][r] - mnew);
        p[nj][r] = e;
        sum += e;
      }
      sum += __shfl_xor(sum, 1);
      sum += __shfl_xor(sum, 2);
      sum += __shfl_xor(sum, 4);
      sum += __shfl_xor(sum, 8);
      lrun[r] = lrun[r] * corr + sum;
      o0[r] *= corr; o1[r] *= corr; o2[r] *= corr; o3[r] *= corr;
#pragma unroll
      for (int nj = 0; nj < 4; ++nj)
        ldsP[w][(myrow + r) * LDK + nj * 16 + col16] = f2bf(p[nj][r]);
    }

    // ---- PV (wave-local P exchange through LDS; compiler orders ds ops) ----
#pragma unroll
    for (int kc = 0; kc < 2; ++kc) {
      bf16x8 pa = *(const bf16x8*)&ldsP[w][col16 * LDK + kc * 32 + (lane >> 4) * 8];
      bf16x8 v0 = *(const bf16x8*)&ldsV[(0 * 16 + col16) * LDK + kc * 32 + (lane >> 4) * 8];
      bf16x8 v1 = *(const bf16x8*)&ldsV[(1 * 16 + col16) * LDK + kc * 32 + (lane >> 4) * 8];
      bf16x8 v2 = *(const bf16x8*)&ldsV[(2 * 16 + col16) * LDK + kc * 32 + (lane >> 4) * 8];
      bf16x8 v3 = *(const bf16x8*)&ldsV[(3 * 16 + col16) * LDK + kc * 32 + (lane >> 4) * 8];
      o0 = mfma16(pa, v0, o0);
      o1 = mfma16(pa, v1, o1);
      o2 = mfma16(pa, v2, o2);
      o3 = mfma16(pa, v3, o3);
    }
  }

  // ---- epilogue: normalize + merge heads ----
#pragma unroll
  for (int r = 0; r < 4; ++r) {
    float inv = 1.f / lrun[r];
    int s = q0 + w * 16 + myrow + r;
    u16* op = aout + (size_t)(b * Ss + s) * Ee + h * HDd + col16;
    op[0]  = f2bf(o0[r] * inv);
    op[16] = f2bf(o1[r] * inv);
    op[32] = f2bf(o2[r] * inv);
    op[48] = f2bf(o3[r] * inv);
  }
}

// ---------------- launch ----------------
extern "C" void kernel_launch(void* const* d_in, const int* in_sizes, int n_in,
                              void* d_out, int out_size, void* d_ws, size_t ws_size,
                              hipStream_t stream) {
  const float* hs        = (const float*)d_in[0];  // [4,2048,1024]
  const float* c_attn_w  = (const float*)d_in[1];  // [1024,3072]
  const float* c_attn_b  = (const float*)d_in[2];  // [3072]
  const float* c_proj_w  = (const float*)d_in[3];  // [1024,1024]
  const float* c_proj_b  = (const float*)d_in[4];  // [1024]
  float* out = (float*)d_out;

  char* ws = (char*)d_ws;
  size_t off = 0;
  u16* xb     = (u16*)(ws + off); off += (size_t)Mm * Ee * 2;        // 16.8 MB
  u16* wqkvt  = (u16*)(ws + off); off += (size_t)N3 * Ee * 2;        // 6.3 MB
  u16* wprojt = (u16*)(ws + off); off += (size_t)Ee * Ee * 2;        // 2.1 MB
  u16* qkv    = (u16*)(ws + off); off += (size_t)Mm * N3 * 2;        // 50.3 MB
  u16* aoutb  = (u16*)(ws + off); off += (size_t)Mm * Ee * 2;        // 16.8 MB
  if (ws_size < off) return;  // fail loudly via validation rather than corrupting

  cast_x_kernel<<<2048, 256, 0, stream>>>(hs, xb, Mm * Ee / 4);
  transpose_cast_kernel<<<dim3(N3 / 32, Ee / 32), 256, 0, stream>>>(c_attn_w, wqkvt, Ee, N3);
  transpose_cast_kernel<<<dim3(Ee / 32, Ee / 32), 256, 0, stream>>>(c_proj_w, wprojt, Ee, Ee);
  gemm_kernel<true><<<dim3(N3 / 128, Mm / 128), 256, 0, stream>>>(
      xb, wqkvt, c_attn_b, qkv, Mm, N3, Ee);
  attn_kernel<<<dim3(Ss / 64, Bb * Hh), 256, 0, stream>>>(qkv, aoutb);
  gemm_kernel<false><<<dim3(Ee / 128, Mm / 128), 256, 0, stream>>>(
      aoutb, wprojt, c_proj_b, out, Mm, Ee, Ee);
}

// Round 2
// 199.053 us; speedup vs baseline: 2.0193x; 2.0193x over previous
//
#include <hip/hip_runtime.h>

typedef __attribute__((ext_vector_type(8))) __bf16 bf16x8;
typedef __attribute__((ext_vector_type(8))) unsigned short u16x8;
typedef __attribute__((ext_vector_type(4))) float f32x4;
typedef __attribute__((ext_vector_type(16))) float f32x16;
typedef __attribute__((ext_vector_type(4))) unsigned int u32x4;
typedef unsigned short u16;
typedef unsigned int u32;

constexpr int Bb = 4, Ss = 2048, Ee = 1024, Hh = 16, HDd = 64;
constexpr int Mm = Bb * Ss;   // 8192
constexpr int N3 = 3 * Ee;    // 3072

__device__ __forceinline__ u16 f2bf(float f) {
  u32 u = __builtin_bit_cast(u32, f);
  u = (u + 0x7FFFu + ((u >> 16) & 1u)) >> 16;
  return (u16)u;
}
__device__ __forceinline__ u32 pk2bf(float a, float b) {
  return (u32)f2bf(a) | ((u32)f2bf(b) << 16);
}

__device__ __forceinline__ void gload_lds16(const void* g, void* l) {
  __builtin_amdgcn_global_load_lds(
      (__attribute__((address_space(1))) void*)g,
      (__attribute__((address_space(3))) void*)l, 16, 0, 0);
}

__device__ __forceinline__ f32x4 mfma16(bf16x8 a, bf16x8 b, f32x4 c) {
  return __builtin_amdgcn_mfma_f32_16x16x32_bf16(a, b, c, 0, 0, 0);
}
__device__ __forceinline__ f32x16 mfma32(bf16x8 a, bf16x8 b, f32x16 c) {
  return __builtin_amdgcn_mfma_f32_32x32x16_bf16(a, b, c, 0, 0, 0);
}

// ---------------- cast fp32 -> bf16, flat, vectorized ----------------
__global__ void cast_x_kernel(const float* __restrict__ x, u16* __restrict__ xb, int n4) {
  int i = blockIdx.x * blockDim.x + threadIdx.x;
  int stride = gridDim.x * blockDim.x;
  for (; i < n4; i += stride) {
    float4 v = reinterpret_cast<const float4*>(x)[i];
    ushort4 o;
    o.x = f2bf(v.x); o.y = f2bf(v.y); o.z = f2bf(v.z); o.w = f2bf(v.w);
    reinterpret_cast<ushort4*>(xb)[i] = o;
  }
}

// ---------------- transpose-cast weight [K][N] fp32 -> [N][K] bf16 ----------------
__global__ void transpose_cast_kernel(const float* __restrict__ W, u16* __restrict__ Wt,
                                      int K, int N) {
  __shared__ float tile[32][33];
  int n0 = blockIdx.x * 32, k0 = blockIdx.y * 32;
  int tx = threadIdx.x & 31, ty = threadIdx.x >> 5;
#pragma unroll
  for (int i = 0; i < 4; ++i)
    tile[ty + i * 8][tx] = W[(size_t)(k0 + ty + i * 8) * N + n0 + tx];
  __syncthreads();
#pragma unroll
  for (int i = 0; i < 4; ++i)
    Wt[(size_t)(n0 + ty + i * 8) * K + k0 + tx] = f2bf(tile[tx][ty + i * 8]);
}

// ---------------- bf16 GEMM: C = A[M][K] * Bt[N][K]^T + bias ----------------
template <bool OUT_BF16>
__global__ __launch_bounds__(256) void gemm_kernel(
    const u16* __restrict__ A, const u16* __restrict__ Bt,
    const float* __restrict__ bias, void* __restrict__ Cout,
    int M, int N, int K) {
  __shared__ __attribute__((aligned(16))) u16 ldsA[128 * 32];
  __shared__ __attribute__((aligned(16))) u16 ldsB[128 * 32];
  int tid = threadIdx.x;
  int lane = tid & 63, w = tid >> 6;
  int wr = w >> 1, wc = w & 1;
  int m0 = blockIdx.y * 128, n0 = blockIdx.x * 128;
  const f32x4 fz = {0.f, 0.f, 0.f, 0.f};
  f32x4 acc[4][4];
#pragma unroll
  for (int mi = 0; mi < 4; ++mi)
#pragma unroll
    for (int nj = 0; nj < 4; ++nj) acc[mi][nj] = fz;

  int srow = tid >> 2;
  int scol = (tid & 3) * 8;
  const u16* aptr = A + (size_t)(m0 + srow) * K + scol;
  const u16* bptr = Bt + (size_t)(n0 + srow) * K + scol;
  u16* la = &ldsA[srow * 32 + scol];
  u16* lb = &ldsB[srow * 32 + scol];

  for (int k0 = 0; k0 < K; k0 += 32) {
    gload_lds16(aptr + k0, la);
    gload_lds16(aptr + k0 + (size_t)64 * K, la + 64 * 32);
    gload_lds16(bptr + k0, lb);
    gload_lds16(bptr + k0 + (size_t)64 * K, lb + 64 * 32);
    __syncthreads();
    bf16x8 af[4], bfr[4];
#pragma unroll
    for (int mi = 0; mi < 4; ++mi)
      af[mi] = *(const bf16x8*)&ldsA[(wr * 64 + mi * 16 + (lane & 15)) * 32 + (lane >> 4) * 8];
#pragma unroll
    for (int nj = 0; nj < 4; ++nj)
      bfr[nj] = *(const bf16x8*)&ldsB[(wc * 64 + nj * 16 + (lane & 15)) * 32 + (lane >> 4) * 8];
#pragma unroll
    for (int mi = 0; mi < 4; ++mi)
#pragma unroll
      for (int nj = 0; nj < 4; ++nj)
        acc[mi][nj] = mfma16(af[mi], bfr[nj], acc[mi][nj]);
    __syncthreads();
  }

#pragma unroll
  for (int mi = 0; mi < 4; ++mi) {
#pragma unroll
    for (int nj = 0; nj < 4; ++nj) {
      int n = n0 + wc * 64 + nj * 16 + (lane & 15);
      float bn = bias[n];
#pragma unroll
      for (int r = 0; r < 4; ++r) {
        int m = m0 + wr * 64 + mi * 16 + (lane >> 4) * 4 + r;
        float v = acc[mi][nj][r] + bn;
        if (OUT_BF16)
          ((u16*)Cout)[(size_t)m * N + n] = f2bf(v);
        else
          ((float*)Cout)[(size_t)m * N + n] = v;
      }
    }
  }
}

// ---------------- causal flash attention, swapped-operand 32x32 ----------------
// qkv layout: [B,S,3E], head h owns cols [h*192, h*192+192) = q(64)|k(64)|v(64)
// grid: (B*H, S/128); 256 threads = 4 waves, wave w owns q rows [q0+32w, +32)
// Per lane: one q-row (col of S^T). Softmax fully in-register + 2 shfl_xor(32).
__global__ __launch_bounds__(256) void attn_kernel(const u16* __restrict__ qkv,
                                                   u16* __restrict__ aout) {
  __shared__ __attribute__((aligned(16))) u16 ldsK[64 * 64];   // [kv][d], XOR-swizzled
  __shared__ __attribute__((aligned(16))) u16 ldsVt[64 * 64];  // [d][kv], XOR-swizzled

  int bh = blockIdx.x;
  int qi = gridDim.y - 1 - blockIdx.y;  // big q-blocks first
  int b = bh >> 4, h = bh & 15;
  int tid = threadIdx.x, lane = tid & 63, w = tid >> 6;
  int hi = lane >> 5, ln31 = lane & 31;
  int q0 = qi * 128;
  int qrow = q0 + w * 32 + ln31;
  int qw_max = q0 + w * 32 + 31;

  const u16* base = qkv + (size_t)b * Ss * N3 + h * (3 * HDd);

  // Q fragments in registers: Q[qrow][16*kc + 8*hi .. +8]
  bf16x8 qf[4];
#pragma unroll
  for (int kc = 0; kc < 4; ++kc)
    qf[kc] = *(const bf16x8*)(base + (size_t)qrow * N3 + kc * 16 + hi * 8);

  f32x16 o[2];
#pragma unroll
  for (int dm = 0; dm < 2; ++dm)
#pragma unroll
    for (int e = 0; e < 16; ++e) o[dm][e] = 0.f;
  float mrun = -__builtin_inff(), lrun = 0.f;

  // per-lane K staging source (pre-swizzled global so LDS stays gload-linear)
  int krsub = lane >> 3;                       // row-within-1KB-chunk
  int kcsub = ((lane & 7) ^ (krsub & 7)) * 8;  // swizzled d-column (u16)

  int ntiles = 2 * qi + 2;
  for (int t = 0; t < ntiles; ++t) {
    int kv0 = t * 64;
    __syncthreads();  // previous tile's LDS readers done
    // ---- stage K via global_load_lds (linear dest, inverse-swizzled src) ----
#pragma unroll
    for (int j = 0; j < 2; ++j) {
      int r = (w * 2 + j) * 8 + krsub;
      const u16* src = base + HDd + (size_t)(kv0 + r) * N3 + kcsub;
      gload_lds16(src, (char*)ldsK + (w * 2 + j) * 1024);
    }
    // ---- stage V transposed + swizzled (reg path) ----
    {
      const u16* vg = base + 2 * HDd + (size_t)(kv0 + lane) * N3;
#pragma unroll
      for (int c = 0; c < 2; ++c) {
        int dc = w + c * 4;
        u16x8 vv = *(const u16x8*)(vg + dc * 8);
#pragma unroll
        for (int i = 0; i < 8; ++i) {
          int d = dc * 8 + i;
          ldsVt[d * 64 + (lane ^ ((d & 7) << 3))] = vv[i];
        }
      }
    }
    __syncthreads();

    if (kv0 <= qw_max) {  // wave-uniform causal skip
      // ---- QK^T swapped: sc[mt] = S^T[32mt+kv', q] ----
      f32x16 sc[2];
#pragma unroll
      for (int mt = 0; mt < 2; ++mt)
#pragma unroll
        for (int e = 0; e < 16; ++e) sc[mt][e] = 0.f;
#pragma unroll
      for (int mt = 0; mt < 2; ++mt) {
        int row = 32 * mt + ln31;
#pragma unroll
        for (int kc = 0; kc < 4; ++kc) {
          bf16x8 kf = *(const bf16x8*)&ldsK[row * 64 + ((kc * 16 + hi * 8) ^ ((row & 7) << 3))];
          sc[mt] = mfma32(kf, qf[kc], sc[mt]);
        }
      }

      // ---- in-register online softmax (lane owns q-row) ----
      float mx = -__builtin_inff();
#pragma unroll
      for (int mt = 0; mt < 2; ++mt)
#pragma unroll
        for (int r = 0; r < 16; ++r) {
          int kvg = kv0 + 32 * mt + (r & 3) + 8 * (r >> 2) + 4 * hi;
          float s = sc[mt][r] * 0.125f;
          s = (kvg > qrow) ? -__builtin_inff() : s;
          sc[mt][r] = s;
          mx = fmaxf(mx, s);
        }
      mx = fmaxf(mx, __shfl_xor(mx, 32));
      float mnew = fmaxf(mrun, mx);
      float corr = __expf(mrun - mnew);
      mrun = mnew;
      float sum = 0.f;
#pragma unroll
      for (int mt = 0; mt < 2; ++mt)
#pragma unroll
        for (int r = 0; r < 16; ++r) {
          float e = __expf(sc[mt][r] - mnew);
          sc[mt][r] = e;
          sum += e;
        }
      sum += __shfl_xor(sum, 32);
      lrun = lrun * corr + sum;
#pragma unroll
      for (int dm = 0; dm < 2; ++dm)
#pragma unroll
        for (int e = 0; e < 16; ++e) o[dm][e] *= corr;

      // ---- P pack to bf16 + xor-32 exchange -> B-frags; PV ----
#pragma unroll
      for (int kw = 0; kw < 4; ++kw) {
        int mt = kw >> 1, k8 = (kw & 1) * 8;
        u32 a0 = pk2bf(sc[mt][k8 + 0], sc[mt][k8 + 1]);
        u32 a1 = pk2bf(sc[mt][k8 + 2], sc[mt][k8 + 3]);
        u32 b0 = pk2bf(sc[mt][k8 + 4], sc[mt][k8 + 5]);
        u32 b1 = pk2bf(sc[mt][k8 + 6], sc[mt][k8 + 7]);
        u32 s0 = hi ? a0 : b0;
        u32 s1 = hi ? a1 : b1;
        u32 r0 = (u32)__shfl_xor((int)s0, 32);
        u32 r1 = (u32)__shfl_xor((int)s1, 32);
        u32x4 fw;
        fw.x = hi ? r0 : a0;
        fw.y = hi ? r1 : a1;
        fw.z = hi ? b0 : r0;
        fw.w = hi ? b1 : r1;
        bf16x8 pf = __builtin_bit_cast(bf16x8, fw);
#pragma unroll
        for (int dm = 0; dm < 2; ++dm) {
          int d = 32 * dm + ln31;
          bf16x8 vf = *(const bf16x8*)&ldsVt[d * 64 + ((kw * 16 + hi * 8) ^ ((d & 7) << 3))];
          o[dm] = mfma32(vf, pf, o[dm]);  // O^T[d][q]
        }
      }
    }
  }

  // ---- epilogue: normalize + merge heads (O^T -> [token][h*64+d]) ----
  float inv = 1.f / lrun;
  u16* orow = aout + (size_t)(b * Ss + qrow) * Ee + h * HDd;
#pragma unroll
  for (int dm = 0; dm < 2; ++dm)
#pragma unroll
    for (int g = 0; g < 4; ++g) {
      ushort4 st;
      st.x = f2bf(o[dm][4 * g + 0] * inv);
      st.y = f2bf(o[dm][4 * g + 1] * inv);
      st.z = f2bf(o[dm][4 * g + 2] * inv);
      st.w = f2bf(o[dm][4 * g + 3] * inv);
      *(ushort4*)(orow + 32 * dm + 8 * g + 4 * hi) = st;
    }
}

// ---------------- launch ----------------
extern "C" void kernel_launch(void* const* d_in, const int* in_sizes, int n_in,
                              void* d_out, int out_size, void* d_ws, size_t ws_size,
                              hipStream_t stream) {
  const float* hs        = (const float*)d_in[0];
  const float* c_attn_w  = (const float*)d_in[1];
  const float* c_attn_b  = (const float*)d_in[2];
  const float* c_proj_w  = (const float*)d_in[3];
  const float* c_proj_b  = (const float*)d_in[4];
  float* out = (float*)d_out;

  char* ws = (char*)d_ws;
  size_t off = 0;
  u16* xb     = (u16*)(ws + off); off += (size_t)Mm * Ee * 2;
  u16* wqkvt  = (u16*)(ws + off); off += (size_t)N3 * Ee * 2;
  u16* wprojt = (u16*)(ws + off); off += (size_t)Ee * Ee * 2;
  u16* qkv    = (u16*)(ws + off); off += (size_t)Mm * N3 * 2;
  u16* aoutb  = (u16*)(ws + off); off += (size_t)Mm * Ee * 2;
  if (ws_size < off) return;

  cast_x_kernel<<<2048, 256, 0, stream>>>(hs, xb, Mm * Ee / 4);
  transpose_cast_kernel<<<dim3(N3 / 32, Ee / 32), 256, 0, stream>>>(c_attn_w, wqkvt, Ee, N3);
  transpose_cast_kernel<<<dim3(Ee / 32, Ee / 32), 256, 0, stream>>>(c_proj_w, wprojt, Ee, Ee);
  gemm_kernel<true><<<dim3(N3 / 128, Mm / 128), 256, 0, stream>>>(
      xb, wqkvt, c_attn_b, qkv, Mm, N3, Ee);
  attn_kernel<<<dim3(Bb * Hh, Ss / 128), 256, 0, stream>>>(qkv, aoutb);
  gemm_kernel<false><<<dim3(Ee / 128, Mm / 128), 256, 0, stream>>>(
      aoutb, wprojt, c_proj_b, out, Mm, Ee, Ee);
}